// Round 2
// 1294.196 us; speedup vs baseline: 1.0288x; 1.0288x over previous
//
#include <hip/hip_runtime.h>

// ObjectMsgEncoder on MI355X. f32 I/O, bf16 MFMA internally (f32 accumulate).
// R22 -> R23: same transposed-GEMM structure as R22 (MFMA16(W_frag, X_frag)
// computes D = W*X^T so each lane holds 4 consecutive columns n0+quad*4+r of
// row mt*16+col; epilogues write one 8B LDS word per fragment; uint2 At
// prefetch; hoisted swizzled addresses + biases). R22 failed absmax=0.244;
// the only unverifiable-new primitive was inline-asm v_cvt_pk_bf16_f32, so
// R23 replaces it with a branch-free manual pack (round-half-up, bit-identical
// to R21's f2b). Everything else unchanged from R22.

typedef __attribute__((ext_vector_type(8))) short short8;
typedef __attribute__((ext_vector_type(4))) float f32x4;

__device__ __forceinline__ float b2f(unsigned short u){
  union { unsigned int i; float f; } v; v.i = ((unsigned int)u) << 16; return v.f;
}
__device__ __forceinline__ float u2f(unsigned int u){
  union { unsigned int i; float f; } v; v.i = u; return v.f;
}
__device__ __forceinline__ unsigned short f2b(float f){
  union { float f; unsigned int i; } v; v.f = f;
  return (unsigned short)((v.i + 0x8000u) >> 16);   // round-half-up
}
// pack two f32 -> bf16x2 in one u32 (lo = bf16(lo), hi = bf16(hi)), round-half-up
__device__ __forceinline__ unsigned int pk2(float lo, float hi){
  union { float f; unsigned int i; } a, b; a.f = lo; b.f = hi;
  return ((a.i + 0x8000u) >> 16) | ((b.i + 0x8000u) & 0xffff0000u);
}
__device__ __forceinline__ float sigm(float x){ return 1.f/(1.f+__expf(-x)); }
__device__ __forceinline__ float tanh_f(float x){ float e = __expf(2.f*x); return 1.f - 2.f/(e+1.f); }
// LDS swizzle: 8-element (16B) chunks, phys chunk = (c&24) | ((c^row)&7).
__device__ __forceinline__ int xsw(int row, int n){
  int c = n >> 3;
  int pc = (c & 24) | ((c ^ row) & 7);
  return row*256 + pc*8 + (n & 7);
}

#define MFMA16(a,b,c) __builtin_amdgcn_mfma_f32_16x16x32_bf16((a),(b),(c),0,0,0)

// ---------------- K0: one-shot repack of all 7 weight blocks + wmean ----------------
__global__ __launch_bounds__(256) void k_repack7(const float* __restrict__ Wih,
                                                 const float* __restrict__ Whh,
                                                 const float* __restrict__ Wgr,
                                                 const float* __restrict__ Wbc,
                                                 const float* __restrict__ Wesa,
                                                 const float* __restrict__ Wmu,
                                                 unsigned short* __restrict__ wcv,
                                                 float* __restrict__ wmean){
  int i = blockIdx.x*256 + threadIdx.x;
  if (i >= 851968){                      // tail block: wmean
    int o = i - 851968;
    if (o < 256) wmean[o] = (Wmu[o] + Wmu[256+o] + Wmu[512+o]) * (1.f/3.f);
    return;
  }
  const float* s; int segbase, N, stride, off, local;
  if      (i < 262144){ s=Wih;  segbase=0;      N=1024; stride=256; off=0;   local=i; }
  else if (i < 524288){ s=Whh;  segbase=262144; N=1024; stride=256; off=0;   local=i-262144; }
  else if (i < 589824){ s=Wgr;  segbase=524288; N=256;  stride=768; off=0;   local=i-524288; }
  else if (i < 655360){ s=Wgr;  segbase=589824; N=256;  stride=768; off=256; local=i-589824; }
  else if (i < 720896){ s=Wgr;  segbase=655360; N=256;  stride=768; off=512; local=i-655360; }
  else if (i < 786432){ s=Wbc;  segbase=720896; N=256;  stride=256; off=0;   local=i-720896; }
  else                { s=Wesa; segbase=786432; N=256;  stride=256; off=0;   local=i-786432; }
  int n = local >> 8, k = local & 255;
  wcv[segbase + (((k >> 3)*N + n) << 3) + (k & 7)] = f2b(s[n*stride + off + k]);
}

// ---------------- K1: olf0 = emb * mask (f32 -> bf16) + zero out ----------------
__global__ __launch_bounds__(256) void k_prep(const float* __restrict__ emb,
                                              const int* __restrict__ counts,
                                              unsigned short* __restrict__ olf,
                                              float* __restrict__ out){
  int bs = blockIdx.x;            // b*28+s
  int b = bs / 28; int s = bs - b*28;
  int e = threadIdx.x;
  olf[(size_t)bs*256 + e] = (s < counts[b]) ? f2b(emb[(size_t)bs*256 + e]) : (unsigned short)0;
  out[(size_t)bs*256 + e] = 0.f;
}

// ---------------- K2a: zx = olf_l @ Wih^T  [7168,256]@[256,1024] -> bf16 ----------------
__global__ __launch_bounds__(256) void k_xgemm(const unsigned short* __restrict__ olf,
                                               const unsigned short* __restrict__ Wih,
                                               unsigned short* __restrict__ zx){
  const int tid = threadIdx.x;
  const int wid = tid >> 6, lane = tid & 63, col = lane & 15, quad = lane >> 4;
  const int m0 = (blockIdx.x >> 1)*64 + wid*16;
  const int nt0 = (blockIdx.x & 1)*32;
  short8 af[8];
  #pragma unroll
  for (int kt=0; kt<8; ++kt)
    af[kt] = *(const short8*)&olf[(size_t)(m0 + col)*256 + kt*32 + quad*8];
  #pragma unroll 4
  for (int nt=nt0; nt<nt0+32; ++nt){
    int n = nt*16 + col;
    f32x4 acc = (f32x4){0.f,0.f,0.f,0.f};
    #pragma unroll
    for (int kt=0; kt<8; ++kt){
      short8 bf = *(const short8*)&Wih[((((kt*4 + quad) << 10) + n) << 3)];
      acc = MFMA16(af[kt], bf, acc);
    }
    #pragma unroll
    for (int r=0; r<4; ++r)
      zx[(size_t)(m0 + quad*4 + r)*1024 + n] = f2b(acc[r]);
  }
}

// ---------------- K2b: FUSED recurrence + A-terms ----------------
__global__ __launch_bounds__(1024) void k_recat(const unsigned short* __restrict__ zx,
                                                const unsigned short* __restrict__ Whh,
                                                const float* __restrict__ bih,
                                                const float* __restrict__ bhh,
                                                const int* __restrict__ counts,
                                                unsigned short* __restrict__ olf_out,
                                                const unsigned short* __restrict__ olf_at,
                                                const unsigned short* __restrict__ Wgri,
                                                const unsigned short* __restrict__ Wgrj,
                                                unsigned short* __restrict__ At_out){
  __shared__ unsigned short Ab[2][16*264];   // used by rec blocks only
  const int tid = threadIdx.x;
  const int wv = tid >> 6, lane = tid & 63, col = lane & 15, quad = lane >> 4;

  if (blockIdx.x >= 16){
    // ---- aterm part: 16 waves x 16 rows = 256 rows per block ----
    const int m0 = (blockIdx.x - 16)*256 + wv*16;
    short8 af[8];
    #pragma unroll
    for (int kt=0; kt<8; ++kt)
      af[kt] = *(const short8*)&olf_at[(size_t)(m0 + col)*256 + kt*32 + quad*8];
    #pragma unroll 4
    for (int nt=0; nt<32; ++nt){
      const unsigned short* wb = (nt < 16) ? Wgri : Wgrj;
      int nn = (nt & 15)*16 + col;
      f32x4 acc = (f32x4){0.f,0.f,0.f,0.f};
      #pragma unroll
      for (int kt=0; kt<8; ++kt){
        short8 bf = *(const short8*)&wb[((((kt*4 + quad) << 8) + nn) << 3)];
        acc = MFMA16(af[kt], bf, acc);
      }
      #pragma unroll
      for (int r=0; r<4; ++r)
        At_out[(size_t)(m0 + quad*4 + r)*512 + nt*16 + col] = f2b(acc[r]);
    }
    return;
  }
  // ---- recurrence part ----
  const int sc0 = blockIdx.x * 16;
  const int u = wv*16 + col;
  float bz[4];
  #pragma unroll
  for (int g=0; g<4; ++g) bz[g] = bih[g*256+u] + bhh[g*256+u];
  int cnt4[4];
  #pragma unroll
  for (int r=0; r<4; ++r) cnt4[r] = counts[sc0 + quad*4 + r];

  float cst[4];
  #pragma unroll
  for (int r=0; r<4; ++r) cst[r] = 0.f;
  for (int i=tid; i<16*264; i+=1024) Ab[0][i] = 0;   // h0 = 0
  __syncthreads();

  for (int t=0; t<28; ++t){
    const int cur = t & 1, nxt = cur ^ 1;
    float zxv[4][4];
    #pragma unroll
    for (int g=0; g<4; ++g){
      #pragma unroll
      for (int r=0; r<4; ++r)
        zxv[g][r] = b2f(zx[((size_t)(sc0 + quad*4 + r)*28 + t)*1024 + g*256 + u]);
    }
    f32x4 acc[4];
    #pragma unroll
    for (int g=0; g<4; ++g) acc[g] = (f32x4){0.f,0.f,0.f,0.f};
    #pragma unroll
    for (int kt=0; kt<8; ++kt){
      short8 a = *(const short8*)&Ab[cur][col*264 + kt*32 + quad*8];
      #pragma unroll
      for (int g=0; g<4; ++g){
        short8 bf = *(const short8*)&Whh[((((kt*4 + quad) << 10) + g*256 + u) << 3)];
        acc[g] = MFMA16(a, bf, acc[g]);
      }
    }
    // no barrier: writes go to Ab[nxt], readers used Ab[cur]
    #pragma unroll
    for (int r=0; r<4; ++r){
      int s = quad*4 + r;
      float zi = acc[0][r] + zxv[0][r] + bz[0];
      float zf = acc[1][r] + zxv[1][r] + bz[1];
      float zg = acc[2][r] + zxv[2][r] + bz[2];
      float zo = acc[3][r] + zxv[3][r] + bz[3];
      float cc = sigm(zf)*cst[r] + sigm(zi)*tanh_f(zg);
      cst[r] = cc;
      float hh = sigm(zo)*tanh_f(cc);
      unsigned short hb = f2b(hh);
      Ab[nxt][s*264 + u] = hb;                              // raw h feeds recurrence
      olf_out[((size_t)(sc0+s)*28 + t)*256 + u] = (t < cnt4[r]) ? hb : (unsigned short)0;
    }
    __syncthreads();   // Ab[nxt] complete before step t+1 reads it
  }
}

// ---------------- K3: A-terms for ONE layer, [7168,256]@[256,512] -> bf16 ----------------
__global__ __launch_bounds__(256) void k_aterm(const unsigned short* __restrict__ olf,
                                               const unsigned short* __restrict__ Wgri,
                                               const unsigned short* __restrict__ Wgrj,
                                               unsigned short* __restrict__ Aout){
  const int tid = threadIdx.x;
  const int wid = tid >> 6, lane = tid & 63, col = lane & 15, quad = lane >> 4;
  const int m0 = blockIdx.x*64 + wid*16;
  short8 af[8];
  #pragma unroll
  for (int kt=0; kt<8; ++kt)
    af[kt] = *(const short8*)&olf[(size_t)(m0 + col)*256 + kt*32 + quad*8];
  #pragma unroll 4
  for (int nt=0; nt<32; ++nt){
    const unsigned short* wb = (nt < 16) ? Wgri : Wgrj;
    int nn = (nt & 15)*16 + col;
    f32x4 acc = (f32x4){0.f,0.f,0.f,0.f};
    #pragma unroll
    for (int kt=0; kt<8; ++kt){
      short8 bf = *(const short8*)&wb[((((kt*4 + quad) << 8) + nn) << 3)];
      acc = MFMA16(af[kt], bf, acc);
    }
    #pragma unroll
    for (int r=0; r<4; ++r)
      Aout[(size_t)(m0 + quad*4 + r)*512 + nt*16 + col] = f2b(acc[r]);
  }
}

// ---------------- K4: fused per-(scene, j-pair), transposed-output GEMMs ----------------
// Ya[mt][nt2] = W-rows(nbase+nt2*16+quad*4+r) x X-row(mt*16+col): D = W*X^T.
// A-operand = weight fragment (rows n), B-operand = LDS X fragment (rows m).
#define GEMM_TILE64(SRC, WPTR)                                                      \
  {                                                                                 \
    _Pragma("unroll")                                                               \
    for (int rf=0; rf<4; ++rf){ Ya[rf][0]=(f32x4){0.f,0.f,0.f,0.f};                 \
                                Ya[rf][1]=(f32x4){0.f,0.f,0.f,0.f}; }               \
    _Pragma("unroll 1")                                                             \
    for (int kc=0; kc<4; ++kc){                                                     \
      short8 av[2][4], bv[2][2];                                                    \
      _Pragma("unroll")                                                             \
      for (int u=0; u<2; ++u){                                                      \
        int kt = kc*2 + u;                                                          \
        _Pragma("unroll")                                                           \
        for (int rf=0; rf<4; ++rf)                                                  \
          av[u][rf] = *(const short8*)&(SRC)[(Abase[rf] + kc*64) ^ (u*32)];         \
        bv[u][0] = *(const short8*)&(WPTR)[Bbase + kt*8192];                        \
        bv[u][1] = *(const short8*)&(WPTR)[Bbase + kt*8192 + 128];                  \
      }                                                                             \
      _Pragma("unroll")                                                             \
      for (int u=0; u<2; ++u){                                                      \
        _Pragma("unroll")                                                           \
        for (int rf=0; rf<4; ++rf){                                                 \
          Ya[rf][0] = MFMA16(bv[u][0], av[u][rf], Ya[rf][0]);                       \
          Ya[rf][1] = MFMA16(bv[u][1], av[u][rf], Ya[rf][1]);                       \
        }                                                                           \
      }                                                                             \
    }                                                                               \
  }

__global__ __launch_bounds__(512) void k_mega(
    const float* __restrict__ centers, const int* __restrict__ counts,
    const float* __restrict__ Wr, const float* __restrict__ br,
    const unsigned short* __restrict__ Wgrr, const float* __restrict__ bgr,
    const unsigned short* __restrict__ Wbc, const float* __restrict__ bbc,
    const float* __restrict__ alpha,
    const unsigned short* __restrict__ Wesa, const float* __restrict__ besa,
    const float* __restrict__ wmean, const float* __restrict__ bmu,
    const unsigned short* __restrict__ Aterm, float* __restrict__ out){
  __shared__ unsigned short Xa[64*256];    // rlf -> E=exp(resa); rows 56..63 pad/stats
  __shared__ unsigned short Yb[64*256];    // rlf_lin / resa
  float* hrSBp = (float*)&Xa[56*256];      // 512 f32 [jc*256+o]: 0.5/sum_i E
  float* gsbp  = (float*)&Xa[60*256];      // 64 f32 per row p: G = exp(gscore)
  float* hrSGp = (float*)&Xa[60*256+128];  // 2 f32 per jc: 0.5/sum_i G
  const int tid = threadIdx.x;
  const int wv = tid >> 6;          // 0..7 -> col slice
  const int lane = tid & 63, col = lane & 15, quad = lane >> 4;
  const int b = blockIdx.x / 14, jt = blockIdx.x - b*14;   // j = jt*2 + jc
  const int cb = counts[b];
  const int nbase = wv*32;

  float av_ = alpha[0];
  float tv = sigm(av_);
  float c1 = (1.f-tv)*(1.f-tv) + tv*tv;
  float c2 = 2.f*tv*(1.f-tv);

  // per-thread row mapping for transposed fragments: m = mt*16 + col
  int pis[4], pjs[4]; float pv[4];
  #pragma unroll
  for (int mt=0; mt<4; ++mt){
    int m = mt*16 + col;
    int i = m >> 1;
    pis[mt] = (i < 27) ? i : 27;
    pjs[mt] = jt*2 + (m & 1);
    pv[mt] = (m < 56 && i < cb && pjs[mt] < cb) ? 1.f : 0.f;
  }
  // hoisted swizzled addresses (reused across all 7 GEMMs / 3 layers)
  int Abase[4];
  #pragma unroll
  for (int rf=0; rf<4; ++rf){
    int row = rf*16 + col;
    Abase[rf] = row*256 + ((quad ^ (row & 3)) | (row & 4))*8;
  }
  const int Bbase = (quad*256 + nbase + col)*8;
  int woff[4][2];
  f32x4 bgv[2], bbv[2], bev[2];
  #pragma unroll
  for (int nt2=0; nt2<2; ++nt2){
    int n0 = nbase + nt2*16 + quad*4;
    bgv[nt2] = *(const f32x4*)&bgr[n0];
    bbv[nt2] = *(const f32x4*)&bbc[n0];
    bev[nt2] = *(const f32x4*)&besa[n0];
    #pragma unroll
    for (int mt=0; mt<4; ++mt)
      woff[mt][nt2] = xsw(mt*16 + col, n0);
  }

  // S0: rlf0[row] -> Xa ; pad rows = 0
  {
    int m = tid >> 3, sub = tid & 7;   // m 0..63, 32 cols each
    int i = m >> 1, j = jt*2 + (m & 1);
    bool valid = (m < 56);
    float mi = (valid && i < cb) ? 1.f : 0.f;
    float mj = (valid && j < cb) ? 1.f : 0.f;
    const float* ci = centers + (b*28 + (valid ? i : 0))*3;
    const float* cj = centers + (b*28 + j)*3;
    float dx = mi*ci[0] - mj*cj[0];
    float dy = mi*ci[1] - mj*cj[1];
    float dz = mi*ci[2] - mj*cj[2];
    for (int e = sub*32; e < sub*32 + 32; ++e){
      float v = valid ? (dx*Wr[e*3] + dy*Wr[e*3+1] + dz*Wr[e*3+2] + br[e]) : 0.f;
      Xa[xsw(m, e)] = f2b(v);
    }
  }
  __syncthreads();

  f32x4 Ya[4][2];
  #pragma unroll 1
  for (int l=0; l<3; ++l){
    // At PREFETCH for this layer's S2 -- 16x 8B loads, issued BEFORE GEMM1
    // (independent of Xa); the waitcnt lands between GEMM1's end and S2.
    const int lb = (l*7168 + b*28)*512;
    uint2 rAi[4][2], rAj[4][2];
    #pragma unroll
    for (int nt2=0; nt2<2; ++nt2){
      int n0 = nbase + nt2*16 + quad*4;
      #pragma unroll
      for (int mt=0; mt<4; ++mt){
        rAi[mt][nt2] = *(const uint2*)&Aterm[lb + pis[mt]*512 + n0];
        rAj[mt][nt2] = *(const uint2*)&Aterm[lb + pjs[mt]*512 + 256 + n0];
      }
    }
    // GEMM1: Wgr_r x rlf(Xa)^T -- then S2 writes Yb (no barrier in between)
    GEMM_TILE64(Xa, Wgrr);
    // S2: rlf_lin = Y + A_i + A_j + bgr -> Yb (packed 8B writes)
    #pragma unroll
    for (int nt2=0; nt2<2; ++nt2){
      #pragma unroll
      for (int mt=0; mt<4; ++mt){
        uint2 wi = rAi[mt][nt2], wj = rAj[mt][nt2];
        float v0 = Ya[mt][nt2][0] + bgv[nt2][0] + u2f(wi.x << 16)         + u2f(wj.x << 16);
        float v1 = Ya[mt][nt2][1] + bgv[nt2][1] + u2f(wi.x & 0xffff0000u) + u2f(wj.x & 0xffff0000u);
        float v2 = Ya[mt][nt2][2] + bgv[nt2][2] + u2f(wi.y << 16)         + u2f(wj.y << 16);
        float v3 = Ya[mt][nt2][3] + bgv[nt2][3] + u2f(wi.y & 0xffff0000u) + u2f(wj.y & 0xffff0000u);
        *(uint2*)&Yb[woff[mt][nt2]] = make_uint2(pk2(v0,v1), pk2(v2,v3));
      }
    }
    __syncthreads();   // Yb complete before GEMM2 reads it
    // GEMM2: Wbc x rlf_lin(Yb)^T -- then S4 writes Xa (no barrier in between)
    GEMM_TILE64(Yb, Wbc);
    // S4: rlf = tanh(c1*rlf_lin + c2*(CP+bbc)) * pv -> Xa
    #pragma unroll
    for (int nt2=0; nt2<2; ++nt2){
      #pragma unroll
      for (int mt=0; mt<4; ++mt){
        uint2 w = *(const uint2*)&Yb[woff[mt][nt2]];
        float r0 = u2f(w.x << 16),         r1 = u2f(w.x & 0xffff0000u);
        float r2 = u2f(w.y << 16),         r3 = u2f(w.y & 0xffff0000u);
        float x0 = tanh_f(c1*r0 + c2*(Ya[mt][nt2][0] + bbv[nt2][0])) * pv[mt];
        float x1 = tanh_f(c1*r1 + c2*(Ya[mt][nt2][1] + bbv[nt2][1])) * pv[mt];
        float x2 = tanh_f(c1*r2 + c2*(Ya[mt][nt2][2] + bbv[nt2][2])) * pv[mt];
        float x3 = tanh_f(c1*r3 + c2*(Ya[mt][nt2][3] + bbv[nt2][3])) * pv[mt];
        *(uint2*)&Xa[woff[mt][nt2]] = make_uint2(pk2(x0,x1), pk2(x2,x3));
      }
    }
    __syncthreads();   // Xa complete before next GEMM1; fences Yb readers vs next S2
  }
  // S5: resa = Wesa x rlf(Xa)^T + besa -> v to Yb, E=exp(v) to Xa
  GEMM_TILE64(Xa, Wesa);
  __syncthreads();   // all GEMM reads of Xa(rlf) done before E overwrites it
  #pragma unroll
  for (int nt2=0; nt2<2; ++nt2){
    #pragma unroll
    for (int mt=0; mt<4; ++mt){
      float v0 = Ya[mt][nt2][0] + bev[nt2][0];
      float v1 = Ya[mt][nt2][1] + bev[nt2][1];
      float v2 = Ya[mt][nt2][2] + bev[nt2][2];
      float v3 = Ya[mt][nt2][3] + bev[nt2][3];
      *(uint2*)&Yb[woff[mt][nt2]] = make_uint2(pk2(v0,v1), pk2(v2,v3));
      *(uint2*)&Xa[woff[mt][nt2]] =
          make_uint2(pk2(__expf(v0),__expf(v1)), pk2(__expf(v2),__expf(v3)));
    }
  }
  __syncthreads();
  // G[row] = exp(gscore) (reads Yb) + SB column sums of E (reads Xa)
  {
    int m = tid >> 3, sub = tid & 7;   // 8 threads per row, 32 cols each
    if (m < 56){
      float s = 0.f;
      for (int e = sub*32; e < sub*32 + 32; ++e)
        s += b2f(Yb[xsw(m, e)]) * wmean[e];
      s += __shfl_xor(s, 1, 64);
      s += __shfl_xor(s, 2, 64);
      s += __shfl_xor(s, 4, 64);
      if (sub == 0)
        gsbp[m] = __expf(s + (bmu[0] + bmu[1] + bmu[2])*(1.f/3.f));
    }
  }
  {
    int jc = tid >> 8, o = tid & 255;  // all 512 threads
    float se = 0.f;
    #pragma unroll
    for (int i=0;i<28;++i) se += b2f(Xa[xsw(i*2+jc, o)]);
    hrSBp[jc*256 + o] = 0.5f / se;
  }
  __syncthreads();
  if (tid < 2){
    int jc = tid;
    float se = 0.f;
    for (int i=0;i<28;++i) se += gsbp[i*2+jc];
    hrSGp[jc] = 0.5f / se;
  }
  __syncthreads();
  // masked output: atomicAdd straight into d_out (zeroed by k_prep)
  for (int it = tid; it < 7168; it += 512){
    int i = it >> 8, o = it & 255;
    if (i < cb){
      float s = 0.f;
      #pragma unroll
      for (int jc=0; jc<2; ++jc){
        int row = i*2 + jc;
        int off = xsw(row, o);
        float v = b2f(Yb[off]);
        float E = b2f(Xa[off]);
        float a = E*hrSBp[jc*256+o] + gsbp[row]*hrSGp[jc];
        s += a * v;
      }
      atomicAdd(&out[((size_t)b*28 + i)*256 + o], s);
    }
  }
}

extern "C" void kernel_launch(void* const* d_in, const int* in_sizes, int n_in,
                              void* d_out, int out_size, void* d_ws, size_t ws_size,
                              hipStream_t stream){
  const float* centers = (const float*)d_in[0];
  const float* emb     = (const float*)d_in[1];
  const int*   counts  = (const int*)d_in[2];
  const float* Wr      = (const float*)d_in[3];
  const float* br      = (const float*)d_in[4];
  const float* Wih     = (const float*)d_in[5];
  const float* Whh     = (const float*)d_in[6];
  const float* bih     = (const float*)d_in[7];
  const float* bhh     = (const float*)d_in[8];
  const float* Wgr     = (const float*)d_in[9];
  const float* bgr     = (const float*)d_in[10];
  const float* Wbc     = (const float*)d_in[11];
  const float* bbc     = (const float*)d_in[12];
  const float* alpha   = (const float*)d_in[13];
  const float* Wesa    = (const float*)d_in[14];
  const float* besa    = (const float*)d_in[15];
  const float* Wmu     = (const float*)d_in[16];
  const float* bmu     = (const float*)d_in[17];
  // d_in[18], d_in[19] (Wlv, blv) are dead at eval time.

  // ws layout (49,415,168 bytes total):
  unsigned short* olf   = (unsigned short*)d_ws;                      // 3*7168*256 bf16 = 11,010,048 B
  unsigned short* At    = (unsigned short*)((char*)d_ws + 11010048);  // 3*7168*512 bf16 = 22,020,096 B
  unsigned short* zx    = (unsigned short*)((char*)d_ws + 33030144);  // 7168*1024 bf16 = 14,680,064 B
  unsigned short* wcv   = (unsigned short*)((char*)d_ws + 47710208);  // 851,968 bf16 = 1,703,936 B
  float*          wmean = (float*)((char*)d_ws + 49414144);           // 256 f32
  unsigned short* cWih  = wcv;            // 262144 (N=1024)
  unsigned short* cWhh  = wcv + 262144;   // 262144 (N=1024)
  unsigned short* cWgri = wcv + 524288;   // 65536  (N=256)
  unsigned short* cWgrj = wcv + 589824;   // 65536  (N=256)
  unsigned short* cWgrr = wcv + 655360;   // 65536  (N=256)
  unsigned short* cWbc  = wcv + 720896;   // 65536  (N=256)
  unsigned short* cWesa = wcv + 786432;   // 65536  (N=256)
  float* outp = (float*)d_out;

  unsigned short* olf1 = olf + (size_t)7168*256;
  unsigned short* olf2 = olf + (size_t)2*7168*256;
  unsigned short* At1  = At  + (size_t)7168*512;
  unsigned short* At2  = At  + (size_t)2*7168*512;

  hipLaunchKernelGGL(k_repack7, dim3(3329), dim3(256), 0, stream,
                     Wih, Whh, Wgr, Wbc, Wesa, Wmu, wcv, wmean);
  hipLaunchKernelGGL(k_prep, dim3(7168), dim3(256), 0, stream, emb, counts, olf, outp);
  // LSTM pass 1 (olf0 -> olf1) fused with A-terms layer 0 (olf0 -> At0)
  hipLaunchKernelGGL(k_xgemm, dim3(224), dim3(256), 0, stream, olf, cWih, zx);
  hipLaunchKernelGGL(k_recat, dim3(44), dim3(1024), 0, stream,
                     zx, cWhh, bih, bhh, counts, olf1, olf, cWgri, cWgrj, At);
  // LSTM pass 2 (olf1 -> olf2) fused with A-terms layer 1 (olf1 -> At1)
  hipLaunchKernelGGL(k_xgemm, dim3(224), dim3(256), 0, stream, olf1, cWih, zx);
  hipLaunchKernelGGL(k_recat, dim3(44), dim3(1024), 0, stream,
                     zx, cWhh, bih, bhh, counts, olf2, olf1, cWgri, cWgrj, At1);
  // A-terms layer 2 (olf2 -> At2)
  hipLaunchKernelGGL(k_aterm, dim3(112), dim3(256), 0, stream, olf2, cWgri, cWgrj, At2);
  hipLaunchKernelGGL(k_mega,  dim3(3584), dim3(512), 0, stream,
                     centers, counts, Wr, br, cWgrr, bgr, cWbc, bbc, alpha,
                     cWesa, besa, wmean, bmu, At, outp);
}